// Round 11
// baseline (267.956 us; speedup 1.0000x reference)
//
#include <hip/hip_runtime.h>

// Bahdanau additive attention, f32 — SINGLE persistent kernel, sw grid barrier.
// B=8, TQ=128, TK=512, NIN=512, H=128, NV=512.
// out = [context (B*TQ*NV), attn (B*TQ*TK)] f32.

#define B_    8
#define TQ_   128
#define TK_   512
#define NIN_  512
#define H_    128
#define NV_   512
#define NQR   (B_*TQ_)           // 1024 query rows
#define NROWS (NQR + B_*TK_)     // 5120 projected rows
#define GRID_ 512                // 2 blocks/CU on 256 CUs: guaranteed co-resident

#define C2_   2.8853900817779268f   // 2*log2(e)
#define L2E_  1.4426950408889634f

__device__ __forceinline__ float fexp2(float x){ return __builtin_amdgcn_exp2f(x); }
__device__ __forceinline__ float frcp (float x){ return __builtin_amdgcn_rcpf(x); }

union Smem {
    struct { float at[32][36]; float wt[32][132]; } p;   // 21.5 KB (max)
    struct { float qs2[2][H_]; float w2[H_]; float sc[2][TK_]; } s;  // 5.6 KB
    struct { float a[8][TK_]; } c;                        // 16 KB
};

// device-scope arrive-and-spin grid barrier (counters zeroed per call).
__device__ __forceinline__ void gbar(unsigned* bar, int i) {
    __syncthreads();
    if (threadIdx.x == 0) {
        __threadfence();
        __hip_atomic_fetch_add(&bar[i], 1u, __ATOMIC_ACQ_REL,
                               __HIP_MEMORY_SCOPE_AGENT);
        while (__hip_atomic_load(&bar[i], __ATOMIC_ACQUIRE,
                                 __HIP_MEMORY_SCOPE_AGENT) < GRID_)
            __builtin_amdgcn_s_sleep(2);
        __threadfence();
    }
    __syncthreads();
}

__global__ __launch_bounds__(256, 2) void fused_kernel(
        const float* __restrict__ query, const float* __restrict__ keys,
        const float* __restrict__ values,
        const float* __restrict__ Wq, const float* __restrict__ bq,
        const float* __restrict__ Wk, const float* __restrict__ bk,
        const float* __restrict__ Wo, const float* __restrict__ bo,
        float* __restrict__ psum, float* __restrict__ pout,
        float* __restrict__ out_ctx, float* __restrict__ out_attn,
        unsigned* __restrict__ bar) {
    __shared__ Smem sm;
    const int tid = threadIdx.x;
    const int bid = blockIdx.x;

    // ========== P1: proj split-K x4 (640 tiles of 32 rows x 128 h) =========
    {
        const int r4  = (tid >> 5) * 4;      // 4 rows
        const int h4  = (tid & 31) * 4;      // 4 h
        const int sr  = tid >> 3;            // stage row 0..31
        const int skq = (tid & 7) * 4;       // stage k quad
        for (int t = bid; t < 640; t += GRID_) {
            const int s    = t / 160;
            const int tile = t - s * 160;
            const int r0   = tile * 32;
            const int kb0  = s * 128;
            const float* in; const float* W;
            if (r0 < NQR) { in = query + (size_t)r0 * NIN_;         W = Wq; }
            else          { in = keys  + (size_t)(r0 - NQR) * NIN_; W = Wk; }

            const float* pA  = in + (size_t)sr * NIN_ + kb0 + skq;
            const float* pW0 = W + (size_t)(sr     ) * NIN_ + kb0 + skq;
            const float* pW1 = W + (size_t)(sr + 32) * NIN_ + kb0 + skq;
            const float* pW2 = W + (size_t)(sr + 64) * NIN_ + kb0 + skq;
            const float* pW3 = W + (size_t)(sr + 96) * NIN_ + kb0 + skq;

            float4 af = *(const float4*)pA;
            float4 w0 = *(const float4*)pW0, w1 = *(const float4*)pW1;
            float4 w2 = *(const float4*)pW2, w3 = *(const float4*)pW3;

            float acc[4][4];
#pragma unroll
            for (int i = 0; i < 4; ++i)
#pragma unroll
                for (int j = 0; j < 4; ++j) acc[i][j] = 0.0f;

            for (int c = 0; c < 4; ++c) {
                __syncthreads();
                sm.p.at[skq+0][sr] = af.x; sm.p.at[skq+1][sr] = af.y;
                sm.p.at[skq+2][sr] = af.z; sm.p.at[skq+3][sr] = af.w;
                sm.p.wt[skq+0][sr   ] = w0.x; sm.p.wt[skq+1][sr   ] = w0.y;
                sm.p.wt[skq+2][sr   ] = w0.z; sm.p.wt[skq+3][sr   ] = w0.w;
                sm.p.wt[skq+0][sr+32] = w1.x; sm.p.wt[skq+1][sr+32] = w1.y;
                sm.p.wt[skq+2][sr+32] = w1.z; sm.p.wt[skq+3][sr+32] = w1.w;
                sm.p.wt[skq+0][sr+64] = w2.x; sm.p.wt[skq+1][sr+64] = w2.y;
                sm.p.wt[skq+2][sr+64] = w2.z; sm.p.wt[skq+3][sr+64] = w2.w;
                sm.p.wt[skq+0][sr+96] = w3.x; sm.p.wt[skq+1][sr+96] = w3.y;
                sm.p.wt[skq+2][sr+96] = w3.z; sm.p.wt[skq+3][sr+96] = w3.w;
                __syncthreads();
                if (c + 1 < 4) {
                    pA += 32; pW0 += 32; pW1 += 32; pW2 += 32; pW3 += 32;
                    af = *(const float4*)pA;
                    w0 = *(const float4*)pW0; w1 = *(const float4*)pW1;
                    w2 = *(const float4*)pW2; w3 = *(const float4*)pW3;
                }
#pragma unroll 8
                for (int kk = 0; kk < 32; ++kk) {
                    const float4 a = *(const float4*)&sm.p.at[kk][r4];
                    const float4 w = *(const float4*)&sm.p.wt[kk][h4];
                    const float av[4] = {a.x, a.y, a.z, a.w};
                    const float wv[4] = {w.x, w.y, w.z, w.w};
#pragma unroll
                    for (int i = 0; i < 4; ++i)
#pragma unroll
                        for (int j = 0; j < 4; ++j)
                            acc[i][j] = fmaf(av[i], wv[j], acc[i][j]);
                }
            }
            float* op = psum + ((size_t)s * NROWS + r0) * H_;
#pragma unroll
            for (int i = 0; i < 4; ++i) {
                float4 o = {acc[i][0], acc[i][1], acc[i][2], acc[i][3]};
                *(float4*)&op[(size_t)(r4 + i) * H_ + h4] = o;
            }
        }
    }
    gbar(bar, 0);

    // ========== P2: reduceP (+bias, *C2) — 320 tiles of 16 rows ============
    {
        for (int t = bid; t < 320; t += GRID_) {
            const int r0 = t * 16;
            const float* bias = (r0 < NQR) ? bq : bk;
#pragma unroll
            for (int p = 0; p < 2; ++p) {
                const int j = tid + p * 256;
                const int row = j >> 5, hq = (j & 31) * 4;
                float4 sv = *(const float4*)&bias[hq];
#pragma unroll
                for (int sp = 0; sp < 4; ++sp) {
                    const float4 v = *(const float4*)
                        &psum[((size_t)sp * NROWS + r0 + row) * H_ + hq];
                    sv.x += v.x; sv.y += v.y; sv.z += v.z; sv.w += v.w;
                }
                float4 o = {sv.x * C2_, sv.y * C2_, sv.z * C2_, sv.w * C2_};
                *(float4*)&pout[(size_t)(r0 + row) * H_ + hq] = o;
            }
        }
    }
    gbar(bar, 1);

    // ========== P3: scores + softmax (512 blocks == NQR/2 exactly) =========
    {
        const int b    = bid >> 6;
        const int q0   = (bid & 63) * 2;
        const int lane = tid & 63;
        const float* qp = pout;
        const float* kp = pout + (size_t)NQR * H_;

        sm.s.qs2[tid >> 7][tid & 127] =
            qp[(size_t)(b * TQ_ + q0 + (tid >> 7)) * H_ + (tid & 127)];
        if (tid < H_) sm.s.w2[tid] = Wo[tid] * -2.0f;
        __syncthreads();

        float sw = sm.s.w2[lane] + sm.s.w2[lane + 64];
#pragma unroll
        for (int m = 1; m < 64; m <<= 1) sw += __shfl_xor(sw, m);
        const float sbase = bo[0] - 0.5f * sw;

#pragma unroll
        for (int half = 0; half < 2; ++half) {
            const int k = tid + half * 256;
            const float4* kp4 = (const float4*)&kp[(size_t)(b * TK_ + k) * H_];
            float s0 = 0.f, s1 = 0.f;
#pragma unroll 4
            for (int hb = 0; hb < 32; ++hb) {
                const float4 kv  = kp4[hb];
                const float4 wv  = *(const float4*)&sm.s.w2[hb * 4];
                const float4 q0v = *(const float4*)&sm.s.qs2[0][hb * 4];
                const float4 q1v = *(const float4*)&sm.s.qs2[1][hb * 4];
                s0 = fmaf(wv.x, frcp(fexp2(q0v.x + kv.x) + 1.f), s0);
                s0 = fmaf(wv.y, frcp(fexp2(q0v.y + kv.y) + 1.f), s0);
                s0 = fmaf(wv.z, frcp(fexp2(q0v.z + kv.z) + 1.f), s0);
                s0 = fmaf(wv.w, frcp(fexp2(q0v.w + kv.w) + 1.f), s0);
                s1 = fmaf(wv.x, frcp(fexp2(q1v.x + kv.x) + 1.f), s1);
                s1 = fmaf(wv.y, frcp(fexp2(q1v.y + kv.y) + 1.f), s1);
                s1 = fmaf(wv.z, frcp(fexp2(q1v.z + kv.z) + 1.f), s1);
                s1 = fmaf(wv.w, frcp(fexp2(q1v.w + kv.w) + 1.f), s1);
            }
            sm.s.sc[0][k] = s0 + sbase;
            sm.s.sc[1][k] = s1 + sbase;
        }
        __syncthreads();

        const int w = tid >> 6;
        if (w < 2) {
            float4 sA = *(const float4*)&sm.s.sc[w][lane * 8];
            float4 sB = *(const float4*)&sm.s.sc[w][lane * 8 + 4];
            float m = fmaxf(fmaxf(fmaxf(sA.x, sA.y), fmaxf(sA.z, sA.w)),
                            fmaxf(fmaxf(sB.x, sB.y), fmaxf(sB.z, sB.w)));
#pragma unroll
            for (int mk = 1; mk < 64; mk <<= 1) m = fmaxf(m, __shfl_xor(m, mk));
            float4 eA, eB;
            eA.x = fexp2((sA.x - m) * L2E_); eA.y = fexp2((sA.y - m) * L2E_);
            eA.z = fexp2((sA.z - m) * L2E_); eA.w = fexp2((sA.w - m) * L2E_);
            eB.x = fexp2((sB.x - m) * L2E_); eB.y = fexp2((sB.y - m) * L2E_);
            eB.z = fexp2((sB.z - m) * L2E_); eB.w = fexp2((sB.w - m) * L2E_);
            float s = eA.x + eA.y + eA.z + eA.w + eB.x + eB.y + eB.z + eB.w;
#pragma unroll
            for (int mk = 1; mk < 64; mk <<= 1) s += __shfl_xor(s, mk);
            const float inv = frcp(s);
            eA.x *= inv; eA.y *= inv; eA.z *= inv; eA.w *= inv;
            eB.x *= inv; eB.y *= inv; eB.z *= inv; eB.w *= inv;
            float4* op = (float4*)
                &out_attn[(size_t)(b * TQ_ + q0 + w) * TK_ + lane * 8];
            op[0] = eA; op[1] = eB;
        }
    }
    gbar(bar, 2);

    // ========== P4: context (512 tiles of 8 q x 128 v, attn in LDS) ========
    {
        const int v0 = (bid & 3) * 128;
        const int qt = bid >> 2;             // 0..127
        const int b  = qt >> 4;
        const int q0 = (qt & 15) * 8;

#pragma unroll
        for (int p = 0; p < 4; ++p) {        // stage attn 8x512 (16 KB)
            const int idx = tid + p * 256;   // float4 index 0..1023
            const int row = idx >> 7, kq = (idx & 127) * 4;
            *(float4*)&sm.c.a[row][kq] =
                *(const float4*)&out_attn[(size_t)(b * TQ_ + q0 + row) * TK_ + kq];
        }
        __syncthreads();

        const int q  = tid >> 5;             // 0..7
        const int v4 = v0 + (tid & 31) * 4;  // 4 v
        const float* vp = values + (size_t)b * TK_ * NV_ + v4;
        float4 acc = {0.f, 0.f, 0.f, 0.f};
#pragma unroll 8
        for (int k = 0; k < TK_; ++k) {
            const float4 vv = *(const float4*)&vp[(size_t)k * NV_];
            const float a = sm.c.a[q][k];
            acc.x = fmaf(a, vv.x, acc.x);
            acc.y = fmaf(a, vv.y, acc.y);
            acc.z = fmaf(a, vv.z, acc.z);
            acc.w = fmaf(a, vv.w, acc.w);
        }
        *(float4*)&out_ctx[(size_t)(b * TQ_ + q0 + q) * NV_ + v4] = acc;
    }
}

// -------------------------------------------------------------- launch ----
extern "C" void kernel_launch(void* const* d_in, const int* in_sizes, int n_in,
                              void* d_out, int out_size, void* d_ws, size_t ws_size,
                              hipStream_t stream) {
    const float* query  = (const float*)d_in[0];
    const float* keys   = (const float*)d_in[1];
    const float* values = (const float*)d_in[2];
    const float* Wq     = (const float*)d_in[3];
    const float* bq     = (const float*)d_in[4];
    const float* Wk     = (const float*)d_in[5];
    const float* bk     = (const float*)d_in[6];
    const float* Wo     = (const float*)d_in[7];
    const float* bo     = (const float*)d_in[8];

    float* out_ctx  = (float*)d_out;                    // B*TQ*NV
    float* out_attn = out_ctx + B_ * TQ_ * NV_;         // B*TQ*TK
    unsigned* bar = (unsigned*)d_ws;                    // 16 uints (3 used)
    float* base = (float*)d_ws + 64;                    // 256 B offset
    float* psum = base;                                 // 4*NROWS*H
    float* pout = psum + (size_t)4 * NROWS * H_;        // NROWS*H (qp|kp, *C2)

    hipMemsetAsync(d_ws, 0, 64, stream);                // zero barrier counters
    fused_kernel<<<GRID_, 256, 0, stream>>>(
        query, keys, values, Wq, bq, Wk, bk, Wo, bo,
        psum, pout, out_ctx, out_attn, bar);
}

// Round 12
// 229.691 us; speedup vs baseline: 1.1666x; 1.1666x over previous
//
#include <hip/hip_runtime.h>

// Bahdanau additive attention, f32 — SINGLE persistent kernel.
// Grid barrier: relaxed-spin + one release/acquire fence pair per block
// (avoids the agent-acquire-per-poll L2 invalidation storm of r11).
// B=8, TQ=128, TK=512, NIN=512, H=128, NV=512.
// out = [context (B*TQ*NV), attn (B*TQ*TK)] f32.

#define B_    8
#define TQ_   128
#define TK_   512
#define NIN_  512
#define H_    128
#define NV_   512
#define NQR   (B_*TQ_)           // 1024 query rows
#define NROWS (NQR + B_*TK_)     // 5120 projected rows
#define GRID_ 512                // 2 blocks/CU on 256 CUs: co-resident

#define C2_   2.8853900817779268f   // 2*log2(e)
#define L2E_  1.4426950408889634f

__device__ __forceinline__ float fexp2(float x){ return __builtin_amdgcn_exp2f(x); }
__device__ __forceinline__ float frcp (float x){ return __builtin_amdgcn_rcpf(x); }

union Smem {
    struct { float at[32][36]; float wt[32][132]; } p;   // 21.5 KB (max)
    struct { float qs2[2][H_]; float w2[H_]; float sc[2][TK_]; } s;  // 5.6 KB
    struct { float a[8][TK_]; } c;                        // 16 KB
};

// Grid barrier: ONE release fence + relaxed arrive, relaxed poll (no cache
// ops per poll), ONE acquire fence after the count completes.
__device__ __forceinline__ void gbar(unsigned* bar, int i) {
    __syncthreads();
    if (threadIdx.x == 0) {
        __threadfence();   // release: write back this block's stores (wbL2)
        __hip_atomic_fetch_add(&bar[i], 1u, __ATOMIC_RELAXED,
                               __HIP_MEMORY_SCOPE_AGENT);
        while (__hip_atomic_load(&bar[i], __ATOMIC_RELAXED,
                                 __HIP_MEMORY_SCOPE_AGENT) < GRID_)
            __builtin_amdgcn_s_sleep(16);
        __threadfence();   // acquire: invalidate once, see others' stores
    }
    __syncthreads();
}

__global__ __launch_bounds__(256, 2) void fused_kernel(
        const float* __restrict__ query, const float* __restrict__ keys,
        const float* __restrict__ values,
        const float* __restrict__ Wq, const float* __restrict__ bq,
        const float* __restrict__ Wk, const float* __restrict__ bk,
        const float* __restrict__ Wo, const float* __restrict__ bo,
        float* __restrict__ psum, float* __restrict__ pout,
        float* __restrict__ out_ctx, float* __restrict__ out_attn,
        unsigned* __restrict__ bar) {
    __shared__ Smem sm;
    const int tid = threadIdx.x;
    const int bid = blockIdx.x;

    // ========== P1: proj split-K x4 (640 tiles of 32 rows x 128 h) =========
    {
        const int r4  = (tid >> 5) * 4;      // 4 rows
        const int h4  = (tid & 31) * 4;      // 4 h
        const int sr  = tid >> 3;            // stage row 0..31
        const int skq = (tid & 7) * 4;       // stage k quad
        for (int t = bid; t < 640; t += GRID_) {
            const int s    = t / 160;
            const int tile = t - s * 160;
            const int r0   = tile * 32;
            const int kb0  = s * 128;
            const float* in; const float* W;
            if (r0 < NQR) { in = query + (size_t)r0 * NIN_;         W = Wq; }
            else          { in = keys  + (size_t)(r0 - NQR) * NIN_; W = Wk; }

            const float* pA  = in + (size_t)sr * NIN_ + kb0 + skq;
            const float* pW0 = W + (size_t)(sr     ) * NIN_ + kb0 + skq;
            const float* pW1 = W + (size_t)(sr + 32) * NIN_ + kb0 + skq;
            const float* pW2 = W + (size_t)(sr + 64) * NIN_ + kb0 + skq;
            const float* pW3 = W + (size_t)(sr + 96) * NIN_ + kb0 + skq;

            float4 af = *(const float4*)pA;
            float4 w0 = *(const float4*)pW0, w1 = *(const float4*)pW1;
            float4 w2 = *(const float4*)pW2, w3 = *(const float4*)pW3;

            float acc[4][4];
#pragma unroll
            for (int i = 0; i < 4; ++i)
#pragma unroll
                for (int j = 0; j < 4; ++j) acc[i][j] = 0.0f;

            for (int c = 0; c < 4; ++c) {
                __syncthreads();
                sm.p.at[skq+0][sr] = af.x; sm.p.at[skq+1][sr] = af.y;
                sm.p.at[skq+2][sr] = af.z; sm.p.at[skq+3][sr] = af.w;
                sm.p.wt[skq+0][sr   ] = w0.x; sm.p.wt[skq+1][sr   ] = w0.y;
                sm.p.wt[skq+2][sr   ] = w0.z; sm.p.wt[skq+3][sr   ] = w0.w;
                sm.p.wt[skq+0][sr+32] = w1.x; sm.p.wt[skq+1][sr+32] = w1.y;
                sm.p.wt[skq+2][sr+32] = w1.z; sm.p.wt[skq+3][sr+32] = w1.w;
                sm.p.wt[skq+0][sr+64] = w2.x; sm.p.wt[skq+1][sr+64] = w2.y;
                sm.p.wt[skq+2][sr+64] = w2.z; sm.p.wt[skq+3][sr+64] = w2.w;
                sm.p.wt[skq+0][sr+96] = w3.x; sm.p.wt[skq+1][sr+96] = w3.y;
                sm.p.wt[skq+2][sr+96] = w3.z; sm.p.wt[skq+3][sr+96] = w3.w;
                __syncthreads();
                if (c + 1 < 4) {
                    pA += 32; pW0 += 32; pW1 += 32; pW2 += 32; pW3 += 32;
                    af = *(const float4*)pA;
                    w0 = *(const float4*)pW0; w1 = *(const float4*)pW1;
                    w2 = *(const float4*)pW2; w3 = *(const float4*)pW3;
                }
#pragma unroll 8
                for (int kk = 0; kk < 32; ++kk) {
                    const float4 a = *(const float4*)&sm.p.at[kk][r4];
                    const float4 w = *(const float4*)&sm.p.wt[kk][h4];
                    const float av[4] = {a.x, a.y, a.z, a.w};
                    const float wv[4] = {w.x, w.y, w.z, w.w};
#pragma unroll
                    for (int i = 0; i < 4; ++i)
#pragma unroll
                        for (int j = 0; j < 4; ++j)
                            acc[i][j] = fmaf(av[i], wv[j], acc[i][j]);
                }
            }
            float* op = psum + ((size_t)s * NROWS + r0) * H_;
#pragma unroll
            for (int i = 0; i < 4; ++i) {
                float4 o = {acc[i][0], acc[i][1], acc[i][2], acc[i][3]};
                *(float4*)&op[(size_t)(r4 + i) * H_ + h4] = o;
            }
        }
    }
    gbar(bar, 0);

    // ========== P2: reduceP (+bias, *C2) — 320 tiles of 16 rows ============
    {
        for (int t = bid; t < 320; t += GRID_) {
            const int r0 = t * 16;
            const float* bias = (r0 < NQR) ? bq : bk;
#pragma unroll
            for (int p = 0; p < 2; ++p) {
                const int j = tid + p * 256;
                const int row = j >> 5, hq = (j & 31) * 4;
                float4 sv = *(const float4*)&bias[hq];
#pragma unroll
                for (int sp = 0; sp < 4; ++sp) {
                    const float4 v = *(const float4*)
                        &psum[((size_t)sp * NROWS + r0 + row) * H_ + hq];
                    sv.x += v.x; sv.y += v.y; sv.z += v.z; sv.w += v.w;
                }
                float4 o = {sv.x * C2_, sv.y * C2_, sv.z * C2_, sv.w * C2_};
                *(float4*)&pout[(size_t)(r0 + row) * H_ + hq] = o;
            }
        }
    }
    gbar(bar, 1);

    // ========== P3: scores + softmax (512 blocks == NQR/2 exactly) =========
    {
        const int b    = bid >> 6;
        const int q0   = (bid & 63) * 2;
        const int lane = tid & 63;
        const float* qp = pout;
        const float* kp = pout + (size_t)NQR * H_;

        sm.s.qs2[tid >> 7][tid & 127] =
            qp[(size_t)(b * TQ_ + q0 + (tid >> 7)) * H_ + (tid & 127)];
        if (tid < H_) sm.s.w2[tid] = Wo[tid] * -2.0f;
        __syncthreads();

        float sw = sm.s.w2[lane] + sm.s.w2[lane + 64];
#pragma unroll
        for (int m = 1; m < 64; m <<= 1) sw += __shfl_xor(sw, m);
        const float sbase = bo[0] - 0.5f * sw;

#pragma unroll
        for (int half = 0; half < 2; ++half) {
            const int k = tid + half * 256;
            const float4* kp4 = (const float4*)&kp[(size_t)(b * TK_ + k) * H_];
            float s0 = 0.f, s1 = 0.f;
#pragma unroll 4
            for (int hb = 0; hb < 32; ++hb) {
                const float4 kv  = kp4[hb];
                const float4 wv  = *(const float4*)&sm.s.w2[hb * 4];
                const float4 q0v = *(const float4*)&sm.s.qs2[0][hb * 4];
                const float4 q1v = *(const float4*)&sm.s.qs2[1][hb * 4];
                s0 = fmaf(wv.x, frcp(fexp2(q0v.x + kv.x) + 1.f), s0);
                s0 = fmaf(wv.y, frcp(fexp2(q0v.y + kv.y) + 1.f), s0);
                s0 = fmaf(wv.z, frcp(fexp2(q0v.z + kv.z) + 1.f), s0);
                s0 = fmaf(wv.w, frcp(fexp2(q0v.w + kv.w) + 1.f), s0);
                s1 = fmaf(wv.x, frcp(fexp2(q1v.x + kv.x) + 1.f), s1);
                s1 = fmaf(wv.y, frcp(fexp2(q1v.y + kv.y) + 1.f), s1);
                s1 = fmaf(wv.z, frcp(fexp2(q1v.z + kv.z) + 1.f), s1);
                s1 = fmaf(wv.w, frcp(fexp2(q1v.w + kv.w) + 1.f), s1);
            }
            sm.s.sc[0][k] = s0 + sbase;
            sm.s.sc[1][k] = s1 + sbase;
        }
        __syncthreads();

        const int w = tid >> 6;
        if (w < 2) {
            float4 sA = *(const float4*)&sm.s.sc[w][lane * 8];
            float4 sB = *(const float4*)&sm.s.sc[w][lane * 8 + 4];
            float m = fmaxf(fmaxf(fmaxf(sA.x, sA.y), fmaxf(sA.z, sA.w)),
                            fmaxf(fmaxf(sB.x, sB.y), fmaxf(sB.z, sB.w)));
#pragma unroll
            for (int mk = 1; mk < 64; mk <<= 1) m = fmaxf(m, __shfl_xor(m, mk));
            float4 eA, eB;
            eA.x = fexp2((sA.x - m) * L2E_); eA.y = fexp2((sA.y - m) * L2E_);
            eA.z = fexp2((sA.z - m) * L2E_); eA.w = fexp2((sA.w - m) * L2E_);
            eB.x = fexp2((sB.x - m) * L2E_); eB.y = fexp2((sB.y - m) * L2E_);
            eB.z = fexp2((sB.z - m) * L2E_); eB.w = fexp2((sB.w - m) * L2E_);
            float s = eA.x + eA.y + eA.z + eA.w + eB.x + eB.y + eB.z + eB.w;
#pragma unroll
            for (int mk = 1; mk < 64; mk <<= 1) s += __shfl_xor(s, mk);
            const float inv = frcp(s);
            eA.x *= inv; eA.y *= inv; eA.z *= inv; eA.w *= inv;
            eB.x *= inv; eB.y *= inv; eB.z *= inv; eB.w *= inv;
            float4* op = (float4*)
                &out_attn[(size_t)(b * TQ_ + q0 + w) * TK_ + lane * 8];
            op[0] = eA; op[1] = eB;
        }
    }
    gbar(bar, 2);

    // ========== P4: context (512 tiles of 8 q x 128 v, attn in LDS) ========
    {
        const int v0 = (bid & 3) * 128;
        const int qt = bid >> 2;             // 0..127
        const int b  = qt >> 4;
        const int q0 = (qt & 15) * 8;

#pragma unroll
        for (int p = 0; p < 4; ++p) {        // stage attn 8x512 (16 KB)
            const int idx = tid + p * 256;   // float4 index 0..1023
            const int row = idx >> 7, kq = (idx & 127) * 4;
            *(float4*)&sm.c.a[row][kq] =
                *(const float4*)&out_attn[(size_t)(b * TQ_ + q0 + row) * TK_ + kq];
        }
        __syncthreads();

        const int q  = tid >> 5;             // 0..7
        const int v4 = v0 + (tid & 31) * 4;  // 4 v
        const float* vp = values + (size_t)b * TK_ * NV_ + v4;
        float4 acc = {0.f, 0.f, 0.f, 0.f};
#pragma unroll 8
        for (int k = 0; k < TK_; ++k) {
            const float4 vv = *(const float4*)&vp[(size_t)k * NV_];
            const float a = sm.c.a[q][k];
            acc.x = fmaf(a, vv.x, acc.x);
            acc.y = fmaf(a, vv.y, acc.y);
            acc.z = fmaf(a, vv.z, acc.z);
            acc.w = fmaf(a, vv.w, acc.w);
        }
        *(float4*)&out_ctx[(size_t)(b * TQ_ + q0 + q) * NV_ + v4] = acc;
    }
}

// -------------------------------------------------------------- launch ----
extern "C" void kernel_launch(void* const* d_in, const int* in_sizes, int n_in,
                              void* d_out, int out_size, void* d_ws, size_t ws_size,
                              hipStream_t stream) {
    const float* query  = (const float*)d_in[0];
    const float* keys   = (const float*)d_in[1];
    const float* values = (const float*)d_in[2];
    const float* Wq     = (const float*)d_in[3];
    const float* bq     = (const float*)d_in[4];
    const float* Wk     = (const float*)d_in[5];
    const float* bk     = (const float*)d_in[6];
    const float* Wo     = (const float*)d_in[7];
    const float* bo     = (const float*)d_in[8];

    float* out_ctx  = (float*)d_out;                    // B*TQ*NV
    float* out_attn = out_ctx + B_ * TQ_ * NV_;         // B*TQ*TK
    unsigned* bar = (unsigned*)d_ws;                    // 16 uints (3 used)
    float* base = (float*)d_ws + 64;                    // 256 B offset
    float* psum = base;                                 // 4*NROWS*H
    float* pout = psum + (size_t)4 * NROWS * H_;        // NROWS*H (qp|kp, *C2)

    hipMemsetAsync(d_ws, 0, 64, stream);                // zero barrier counters
    fused_kernel<<<GRID_, 256, 0, stream>>>(
        query, keys, values, Wq, bq, Wk, bk, Wo, bo,
        psum, pout, out_ctx, out_attn, bar);
}

// Round 13
// 78.384 us; speedup vs baseline: 3.4185x; 2.9303x over previous
//
#include <hip/hip_runtime.h>

// Bahdanau additive attention, f32, 4 kernels.
// B=8, TQ=128, TK=512, NIN=512, H=128, NV=512.
// out = [context (B*TQ*NV), attn (B*TQ*TK)] f32.

#define B_    8
#define TQ_   128
#define TK_   512
#define NIN_  512
#define H_    128
#define NV_   512
#define NQR   (B_*TQ_)           // 1024 query rows
#define NROWS (NQR + B_*TK_)     // 5120 projected rows

#define C2_   2.8853900817779268f   // 2*log2(e)
#define L2E_  1.4426950408889634f

__device__ __forceinline__ float fexp2(float x){ return __builtin_amdgcn_exp2f(x); }
__device__ __forceinline__ float frcp (float x){ return __builtin_amdgcn_rcpf(x); }

// ---------------------------------------------------------------- proj ----
// psum[s][row][h] = A[row, ks:ke) . W[h, ks:ke)
// 256 thr, tile 16 rows x 128 h, 2x4 microtile, kper=128 (4 chunks of 32).
// grid (320, 4) = 1280 blocks x 4 waves = 5 waves/SIMD.
__global__ __launch_bounds__(256, 5) void proj_kernel(
        const float* __restrict__ query, const float* __restrict__ keys,
        const float* __restrict__ Wq, const float* __restrict__ Wk,
        float* __restrict__ psum, int kper) {
    __shared__ float at[32][18];     // [kk][row], 16 rows
    __shared__ float wt[32][132];    // [kk][h], 128 h
    const int tid = threadIdx.x;
    const int r0  = blockIdx.x * 16;
    const float* in; const float* W;
    if (r0 < NQR) { in = query + (size_t)r0 * NIN_;         W = Wq; }
    else          { in = keys  + (size_t)(r0 - NQR) * NIN_; W = Wk; }

    const int r2 = (tid >> 5) * 2;       // 2 rows
    const int h4 = (tid & 31) * 4;       // 4 h
    const int ar  = tid >> 4;            // A-stage row 0..15
    const int ak2 = (tid & 15) * 2;      // A-stage k pair
    const int wr  = tid >> 3;            // W-stage h 0..31 (+32p)
    const int wkq = (tid & 7) * 4;       // W-stage k quad
    const int kb0 = blockIdx.y * kper;
    const int nc  = kper >> 5;

    const float* pA  = in + (size_t)ar * NIN_ + kb0 + ak2;
    const float* pW0 = W + (size_t)(wr     ) * NIN_ + kb0 + wkq;
    const float* pW1 = W + (size_t)(wr + 32) * NIN_ + kb0 + wkq;
    const float* pW2 = W + (size_t)(wr + 64) * NIN_ + kb0 + wkq;
    const float* pW3 = W + (size_t)(wr + 96) * NIN_ + kb0 + wkq;

    float2 af = *(const float2*)pA;
    float4 w0 = *(const float4*)pW0, w1 = *(const float4*)pW1;
    float4 w2 = *(const float4*)pW2, w3 = *(const float4*)pW3;

    float acc[2][4] = {{0.f,0.f,0.f,0.f},{0.f,0.f,0.f,0.f}};

    for (int c = 0; c < nc; ++c) {
        __syncthreads();
        at[ak2+0][ar] = af.x; at[ak2+1][ar] = af.y;
        wt[wkq+0][wr   ] = w0.x; wt[wkq+1][wr   ] = w0.y;
        wt[wkq+2][wr   ] = w0.z; wt[wkq+3][wr   ] = w0.w;
        wt[wkq+0][wr+32] = w1.x; wt[wkq+1][wr+32] = w1.y;
        wt[wkq+2][wr+32] = w1.z; wt[wkq+3][wr+32] = w1.w;
        wt[wkq+0][wr+64] = w2.x; wt[wkq+1][wr+64] = w2.y;
        wt[wkq+2][wr+64] = w2.z; wt[wkq+3][wr+64] = w2.w;
        wt[wkq+0][wr+96] = w3.x; wt[wkq+1][wr+96] = w3.y;
        wt[wkq+2][wr+96] = w3.z; wt[wkq+3][wr+96] = w3.w;
        __syncthreads();
        if (c + 1 < nc) {
            pA += 32; pW0 += 32; pW1 += 32; pW2 += 32; pW3 += 32;
            af = *(const float2*)pA;
            w0 = *(const float4*)pW0; w1 = *(const float4*)pW1;
            w2 = *(const float4*)pW2; w3 = *(const float4*)pW3;
        }
#pragma unroll 8
        for (int kk = 0; kk < 32; ++kk) {
            const float2 a = *(const float2*)&at[kk][r2];
            const float4 w = *(const float4*)&wt[kk][h4];
            acc[0][0] = fmaf(a.x, w.x, acc[0][0]);
            acc[0][1] = fmaf(a.x, w.y, acc[0][1]);
            acc[0][2] = fmaf(a.x, w.z, acc[0][2]);
            acc[0][3] = fmaf(a.x, w.w, acc[0][3]);
            acc[1][0] = fmaf(a.y, w.x, acc[1][0]);
            acc[1][1] = fmaf(a.y, w.y, acc[1][1]);
            acc[1][2] = fmaf(a.y, w.z, acc[1][2]);
            acc[1][3] = fmaf(a.y, w.w, acc[1][3]);
        }
    }

    float* op = psum + ((size_t)blockIdx.y * NROWS + r0) * H_;
#pragma unroll
    for (int i = 0; i < 2; ++i) {
        float4 o = {acc[i][0], acc[i][1], acc[i][2], acc[i][3]};
        *(float4*)&op[(size_t)(r2 + i) * H_ + h4] = o;
    }
}

// ------------------------------------------------------------- reduceP ----
// pout[row][h] = (sum_s psum[s][row][h] + bias[h]) * C2
__global__ __launch_bounds__(256, 4) void reduceP_kernel(
        const float* __restrict__ psum, const float* __restrict__ bq,
        const float* __restrict__ bk, float* __restrict__ pout) {
    const int tid = threadIdx.x;
    const int r0  = blockIdx.x * 8;
    const float* bias = (r0 < NQR) ? bq : bk;
    const int row = tid >> 5, hq = (tid & 31) * 4;
    float4 s = *(const float4*)&bias[hq];
#pragma unroll
    for (int sp = 0; sp < 4; ++sp) {
        float4 v = *(const float4*)&psum[((size_t)sp * NROWS + r0 + row) * H_ + hq];
        s.x += v.x; s.y += v.y; s.z += v.z; s.w += v.w;
    }
    float4 o = {s.x * C2_, s.y * C2_, s.z * C2_, s.w * C2_};
    *(float4*)&pout[(size_t)(r0 + row) * H_ + hq] = o;
}

// -------------------------------------------------------------- scores ----
// Per block: batch b, 2 q rows. Inputs pre-scaled by C2 (bias folded).
// score = bo + sumWo - 2*sum_h Wo_h/(e^(2x_h)+1); softmax over k.
__global__ __launch_bounds__(256, 4) void scores_kernel(
        const float* __restrict__ qp, const float* __restrict__ kp,
        const float* __restrict__ Wo, const float* __restrict__ bo,
        float* __restrict__ out_attn) {
    __shared__ float qs2[2][H_];
    __shared__ float w2[H_];
    __shared__ float sc[2][TK_];

    const int tid = threadIdx.x;
    const int b   = blockIdx.y;
    const int q0  = blockIdx.x * 2;
    const int lane = tid & 63;

    qs2[tid >> 7][tid & 127] =
        qp[(size_t)(b * TQ_ + q0 + (tid >> 7)) * H_ + (tid & 127)];
    if (tid < H_) w2[tid] = Wo[tid] * -2.0f;
    __syncthreads();

    float sw = w2[lane] + w2[lane + 64];
#pragma unroll
    for (int m = 1; m < 64; m <<= 1) sw += __shfl_xor(sw, m);
    const float sbase = bo[0] - 0.5f * sw;

#pragma unroll
    for (int half = 0; half < 2; ++half) {
        const int k = tid + half * 256;
        const float4* kp4 = (const float4*)&kp[(size_t)(b * TK_ + k) * H_];
        float s0 = 0.f, s1 = 0.f;
#pragma unroll 4
        for (int hb = 0; hb < 32; ++hb) {
            const float4 kv  = kp4[hb];
            const float4 wv  = *(const float4*)&w2[hb * 4];
            const float4 q0v = *(const float4*)&qs2[0][hb * 4];
            const float4 q1v = *(const float4*)&qs2[1][hb * 4];
            s0 = fmaf(wv.x, frcp(fexp2(q0v.x + kv.x) + 1.f), s0);
            s0 = fmaf(wv.y, frcp(fexp2(q0v.y + kv.y) + 1.f), s0);
            s0 = fmaf(wv.z, frcp(fexp2(q0v.z + kv.z) + 1.f), s0);
            s0 = fmaf(wv.w, frcp(fexp2(q0v.w + kv.w) + 1.f), s0);
            s1 = fmaf(wv.x, frcp(fexp2(q1v.x + kv.x) + 1.f), s1);
            s1 = fmaf(wv.y, frcp(fexp2(q1v.y + kv.y) + 1.f), s1);
            s1 = fmaf(wv.z, frcp(fexp2(q1v.z + kv.z) + 1.f), s1);
            s1 = fmaf(wv.w, frcp(fexp2(q1v.w + kv.w) + 1.f), s1);
        }
        sc[0][k] = s0 + sbase;
        sc[1][k] = s1 + sbase;
    }
    __syncthreads();

    const int w = tid >> 6;
    if (w < 2) {
        float4 sA = *(const float4*)&sc[w][lane * 8];
        float4 sB = *(const float4*)&sc[w][lane * 8 + 4];
        float m = fmaxf(fmaxf(fmaxf(sA.x, sA.y), fmaxf(sA.z, sA.w)),
                        fmaxf(fmaxf(sB.x, sB.y), fmaxf(sB.z, sB.w)));
#pragma unroll
        for (int mk = 1; mk < 64; mk <<= 1) m = fmaxf(m, __shfl_xor(m, mk));
        float4 eA, eB;
        eA.x = fexp2((sA.x - m) * L2E_); eA.y = fexp2((sA.y - m) * L2E_);
        eA.z = fexp2((sA.z - m) * L2E_); eA.w = fexp2((sA.w - m) * L2E_);
        eB.x = fexp2((sB.x - m) * L2E_); eB.y = fexp2((sB.y - m) * L2E_);
        eB.z = fexp2((sB.z - m) * L2E_); eB.w = fexp2((sB.w - m) * L2E_);
        float s = eA.x + eA.y + eA.z + eA.w + eB.x + eB.y + eB.z + eB.w;
#pragma unroll
        for (int mk = 1; mk < 64; mk <<= 1) s += __shfl_xor(s, mk);
        const float inv = frcp(s);
        eA.x *= inv; eA.y *= inv; eA.z *= inv; eA.w *= inv;
        eB.x *= inv; eB.y *= inv; eB.z *= inv; eB.w *= inv;
        float4* op = (float4*)&out_attn[(size_t)(b * TQ_ + q0 + w) * TK_ + lane * 8];
        op[0] = eA; op[1] = eB;
    }
}

// ------------------------------------------------------------- context ----
// One kernel, no split-K, no reduce: attn tile (8 q x 512 k) staged in LDS,
// values streamed from L2 as float4. 512 blocks x 256 thr.
// Block mapping bid = qt*32 + (b*4+vs): the 16 q-tile blocks sharing one
// (b, v-slab) have bid ≡ pair (mod 32) → same XCD (bid%8) → values slab is
// fetched to that XCD's L2 exactly once (XCD-aware swizzle).
__global__ __launch_bounds__(256, 2) void context_kernel(
        const float* __restrict__ attn, const float* __restrict__ values,
        float* __restrict__ outc) {
    __shared__ float asm_[8][TK_];    // 16 KB

    const int tid  = threadIdx.x;
    const int pair = blockIdx.x & 31;     // (b, v-slab)
    const int qt   = blockIdx.x >> 5;     // q-tile 0..15
    const int b    = pair >> 2;
    const int v0   = (pair & 3) * 128;
    const int q0   = qt * 8;

#pragma unroll
    for (int p = 0; p < 4; ++p) {         // stage attn 8x512
        const int idx = tid + p * 256;    // float4 index 0..1023
        const int row = idx >> 7, kq = (idx & 127) * 4;
        *(float4*)&asm_[row][kq] =
            *(const float4*)&attn[(size_t)(b * TQ_ + q0 + row) * TK_ + kq];
    }
    __syncthreads();

    const int q  = tid >> 5;              // 0..7
    const int v4 = v0 + (tid & 31) * 4;   // 4 v
    const float* vp = values + (size_t)b * TK_ * NV_ + v4;
    float4 acc = {0.f, 0.f, 0.f, 0.f};
#pragma unroll 8
    for (int k = 0; k < TK_; ++k) {
        const float4 vv = *(const float4*)&vp[(size_t)k * NV_];
        const float a = asm_[q][k];
        acc.x = fmaf(a, vv.x, acc.x);
        acc.y = fmaf(a, vv.y, acc.y);
        acc.z = fmaf(a, vv.z, acc.z);
        acc.w = fmaf(a, vv.w, acc.w);
    }
    *(float4*)&outc[(size_t)(b * TQ_ + q0 + q) * NV_ + v4] = acc;
}

// -------------------------------------------------------------- launch ----
extern "C" void kernel_launch(void* const* d_in, const int* in_sizes, int n_in,
                              void* d_out, int out_size, void* d_ws, size_t ws_size,
                              hipStream_t stream) {
    const float* query  = (const float*)d_in[0];
    const float* keys   = (const float*)d_in[1];
    const float* values = (const float*)d_in[2];
    const float* Wq     = (const float*)d_in[3];
    const float* bq     = (const float*)d_in[4];
    const float* Wk     = (const float*)d_in[5];
    const float* bk     = (const float*)d_in[6];
    const float* Wo     = (const float*)d_in[7];
    const float* bo     = (const float*)d_in[8];

    float* out_ctx  = (float*)d_out;                 // B*TQ*NV
    float* out_attn = out_ctx + B_ * TQ_ * NV_;      // B*TQ*TK
    float* pout  = (float*)d_ws;                     // NROWS*H (qp,kp; *C2)
    float* qp    = pout;
    float* kp    = pout + (size_t)NQR * H_;
    float* psumP = pout + (size_t)NROWS * H_;        // 4*NROWS*H

    proj_kernel<<<dim3(NROWS / 16, 4), 256, 0, stream>>>(
        query, keys, Wq, Wk, psumP, NIN_ / 4);
    reduceP_kernel<<<NROWS / 8, 256, 0, stream>>>(psumP, bq, bk, pout);
    scores_kernel<<<dim3(TQ_ / 2, B_), 256, 0, stream>>>(qp, kp, Wo, bo, out_attn);
    context_kernel<<<512, 256, 0, stream>>>(out_attn, values, out_ctx);
}